// Round 21
// baseline (35.687 us; speedup 1.0000x reference)
//
#include <hip/hip_runtime.h>

// PiecewiseHawkesIntensity — np-golden semantics (FROZEN since r11, passed):
//   inv = fl32(1/nc) (CR);  qn = fl32(q * inv)   [reciprocal-multiply key]
//   lo = searchsorted_LEFT(ev, qn); last = lo-1
//   i = clip(last,0); t_last = (last==-1)?0:ev[last]; dt = qn - t_last  (f32)
//   I = (mu_i + (alpha_i - mu_i)*exp(-beta_i*dt)) * inv
//
// r21: WIDE LOADS. 8 schedule variants all ~33us with scalar (4B/lane) param
// loads = 96 VMEM instr/thread; effective BW stuck at 3.6 TB/s = 56% of the
// float4-copy ceiling. This round: 4-row staging intervals, params loaded as
// global_load_dwordx4 (3/thread/interval, 4x fewer+wider requests) and staged
// with ds_write_b128. Gathers kept b32 (r13-identical) for attribution.
// Occupancy 1 block/CU (r20 proved occupancy is irrelevant).

constexpr int B  = 16;
constexpr int M  = 32;
constexpr int P  = 16;
constexpr int L  = 1024;
constexpr int LE = 2048;
constexpr int RI = 4;              // rows per staging interval
constexpr int NI = M / RI;         // 8 intervals

typedef float fx2 __attribute__((ext_vector_type(2)));

__global__ __launch_bounds__(1024)
void hawkes_kernel(const float* __restrict__ qt,   // [B,P,LE]
                   const float* __restrict__ ev,   // [B,P,L]
                   const float* __restrict__ mu,   // [B,M,P,L]
                   const float* __restrict__ al,   // [B,M,P,L]
                   const float* __restrict__ be,   // [B,M,P,L]
                   const float* __restrict__ nc,   // [B]
                   float* __restrict__ out)        // [B,M,P,LE]
{
    __shared__ float s_ev[L];                // 4 KB
    __shared__ float s_mu[2][RI][L];         // 32 KB
    __shared__ float s_al[2][RI][L];         // 32 KB
    __shared__ float s_be[2][RI][L];         // 32 KB

    const int bp = blockIdx.x;          // 0..255  -> (b,p)
    const int b  = bp >> 4;
    const int p  = bp & (P - 1);
    const int t  = threadIdx.x;         // 0..1023

    const float norm     = nc[b];
    const float inv_norm = (float)(1.0 / (double)norm);   // CR f32 recip

    const size_t row0 = ((size_t)b * M * P + p) * L;   // [b,0,p,0]
    const size_t mstr = (size_t)P * L;                 // m-stride

    // staging geometry: thread t covers elements 4*(t&255)..+3 of row (t>>8)
    const int sr = t >> 8;              // 0..3  (row within interval)
    const int sc = (t & 255) * 4;       // element base
    const size_t soff = (size_t)sr * mstr + sc;   // offset of this thread's 16B

    // prologue: ev + interval 0 (regs A) + interval 1 (regs B), all independent
    const float e_in = ev[(size_t)bp * L + t];
    float4 Am, Aa, Ab, Bm, Ba, Bb;
    Am = *reinterpret_cast<const float4*>(mu + row0 + soff);
    Aa = *reinterpret_cast<const float4*>(al + row0 + soff);
    Ab = *reinterpret_cast<const float4*>(be + row0 + soff);
    {
        const size_t r1 = row0 + (size_t)RI * mstr + soff;
        Bm = *reinterpret_cast<const float4*>(mu + r1);
        Ba = *reinterpret_cast<const float4*>(al + r1);
        Bb = *reinterpret_cast<const float4*>(be + r1);
    }

    s_ev[t] = e_in;
    *reinterpret_cast<float4*>(&s_mu[0][sr][sc]) = Am;
    *reinterpret_cast<float4*>(&s_al[0][sr][sc]) = Aa;
    *reinterpret_cast<float4*>(&s_be[0][sr][sc]) = Ab;

    __syncthreads();   // s_ev + buf0 visible (B regs still in flight)

    // two ADJACENT queries per thread (float2 I/O), fixed-trip interleaved search
    const float2 q2 = *reinterpret_cast<const float2*>(qt + (size_t)bp * LE + 2 * t);
    int   idx0, idx1;
    float dt0, dt1;
    {
        float qn[2] = { __fmul_rn(q2.x, inv_norm), __fmul_rn(q2.y, inv_norm) };
        int lo[2] = {0, 0}, hi[2] = {L, L};
#pragma unroll
        for (int s = 0; s < 11; ++s) {     // max path length over 1025 answers
#pragma unroll
            for (int k = 0; k < 2; ++k) {
                if (lo[k] < hi[k]) {       // guard: converged lanes stay put
                    const int mid = (lo[k] + hi[k]) >> 1;
                    if (s_ev[mid] < qn[k]) lo[k] = mid + 1; else hi[k] = mid;
                }
            }
        }
        const int l0 = lo[0] - 1, l1 = lo[1] - 1;
        idx0 = (l0 < 0) ? 0 : l0;   dt0 = qn[0] - ((l0 < 0) ? 0.0f : s_ev[idx0]);
        idx1 = (l1 < 0) ? 0 : l1;   dt1 = qn[1] - ((l1 < 0) ? 0.0f : s_ev[idx1]);
    }

    float* const obase = out + ((size_t)b * M * P + p) * LE + 2 * t;
    const size_t ostr  = (size_t)P * LE;   // out m-stride

#define COMPUTE_INTERVAL(BUF, mbase)                                           \
    _Pragma("unroll")                                                          \
    for (int mm = 0; mm < RI; ++mm) {                                          \
        fx2 o;                                                                 \
        {                                                                      \
            const float m0 = s_mu[BUF][mm][idx0];                              \
            const float a0 = s_al[BUF][mm][idx0];                              \
            const float b0 = s_be[BUF][mm][idx0];                              \
            o.x = fmaf(a0 - m0, __expf(-b0 * dt0), m0) * inv_norm;             \
        }                                                                      \
        {                                                                      \
            const float m1 = s_mu[BUF][mm][idx1];                              \
            const float a1 = s_al[BUF][mm][idx1];                              \
            const float b1 = s_be[BUF][mm][idx1];                              \
            o.y = fmaf(a1 - m1, __expf(-b1 * dt1), m1) * inv_norm;             \
        }                                                                      \
        __builtin_nontemporal_store(                                           \
            o, reinterpret_cast<fx2*>(obase + (size_t)((mbase) + mm) * ostr)); \
    }

#pragma unroll 1
    for (int j = 0; j < NI / 2; ++j) {          // intervals 2j (A) and 2j+1 (B)
        // ---- sub-iter A: compute interval 2j from buf0; A regs free -> 2j+2
        if (2 * j + 2 < NI) {
            const size_t r = row0 + (size_t)(2 * j + 2) * RI * mstr + soff;
            Am = *reinterpret_cast<const float4*>(mu + r);
            Aa = *reinterpret_cast<const float4*>(al + r);
            Ab = *reinterpret_cast<const float4*>(be + r);
        }
        COMPUTE_INTERVAL(0, 2 * j * RI)
        // stage interval 2j+1 (B regs, issued one full sub-iter ago) -> buf1
        *reinterpret_cast<float4*>(&s_mu[1][sr][sc]) = Bm;
        *reinterpret_cast<float4*>(&s_al[1][sr][sc]) = Ba;
        *reinterpret_cast<float4*>(&s_be[1][sr][sc]) = Bb;
        __syncthreads();   // buf1 visible; all readers of buf0 done

        // ---- sub-iter B: compute interval 2j+1 from buf1; B regs free -> 2j+3
        if (2 * j + 3 < NI) {
            const size_t r = row0 + (size_t)(2 * j + 3) * RI * mstr + soff;
            Bm = *reinterpret_cast<const float4*>(mu + r);
            Ba = *reinterpret_cast<const float4*>(al + r);
            Bb = *reinterpret_cast<const float4*>(be + r);
        }
        COMPUTE_INTERVAL(1, (2 * j + 1) * RI)
        // stage interval 2j+2 (A regs) -> buf0
        if (2 * j + 2 < NI) {
            *reinterpret_cast<float4*>(&s_mu[0][sr][sc]) = Am;
            *reinterpret_cast<float4*>(&s_al[0][sr][sc]) = Aa;
            *reinterpret_cast<float4*>(&s_be[0][sr][sc]) = Ab;
        }
        __syncthreads();   // buf0 visible; all readers of buf1 done
    }
#undef COMPUTE_INTERVAL
}

extern "C" void kernel_launch(void* const* d_in, const int* in_sizes, int n_in,
                              void* d_out, int out_size, void* d_ws, size_t ws_size,
                              hipStream_t stream) {
    const float* qt = (const float*)d_in[0];
    const float* ev = (const float*)d_in[1];
    const float* mu = (const float*)d_in[2];
    const float* al = (const float*)d_in[3];
    const float* be = (const float*)d_in[4];
    const float* nc = (const float*)d_in[5];
    float* out = (float*)d_out;

    hawkes_kernel<<<B * P, 1024, 0, stream>>>(qt, ev, mu, al, be, nc, out);
}